// Round 2
// baseline (120.625 us; speedup 1.0000x reference)
//
#include <hip/hip_runtime.h>

// Problem constants (match reference)
#define BB 64
#define PP 8400
#define TT 100

// Kernel 1: one block per (b, t). Each block argmaxes IoU over P predictions
// and writes the masked squared-error contribution to ws[b*T + t].
__global__ __launch_bounds__(256) void yolo_match_kernel(
    const float* __restrict__ pred,    // [B, P, 5]
    const float* __restrict__ tgt,     // [B, T, 5]
    const int*   __restrict__ lengths, // [B] (int32 per harness convention)
    float* __restrict__ ws)            // [B*T] partial sums
{
#pragma clang fp contract(off)
    const int bt  = blockIdx.x;
    const int b   = bt / TT;
    const int t   = bt - b * TT;
    const int tid = threadIdx.x;

    const float* pb = pred + (size_t)b * PP * 5;
    const float* tb = tgt  + ((size_t)b * TT + t) * 5;

    // Target corners (exactly as reference: c - w/2, c + w/2)
    const float tcx = tb[1], tcy = tb[2], tw = tb[3], th = tb[4];
    const float tx1 = tcx - tw * 0.5f;
    const float ty1 = tcy - th * 0.5f;
    const float tx2 = tcx + tw * 0.5f;
    const float ty2 = tcy + th * 0.5f;
    const float area_t = (tx2 - tx1) * (ty2 - ty1);

    float best = -1.0f;   // all IoUs >= 0, so p=0 always beats this
    int   bidx = 0;

    for (int p = tid; p < PP; p += 256) {
        const float* bp = pb + p * 5;
        const float cx = bp[1], cy = bp[2], w = bp[3], h = bp[4];
        const float px1 = cx - w * 0.5f;
        const float py1 = cy - h * 0.5f;
        const float px2 = cx + w * 0.5f;
        const float py2 = cy + h * 0.5f;

        const float ix1 = fmaxf(px1, tx1);
        const float iy1 = fmaxf(py1, ty1);
        const float ix2 = fminf(px2, tx2);
        const float iy2 = fminf(py2, ty2);

        const float inter  = fmaxf(ix2 - ix1, 0.0f) * fmaxf(iy2 - iy1, 0.0f);
        const float area_p = (px2 - px1) * (py2 - py1);
        // numpy eval order: ((area_p + area_t) - inter) + 1e-6
        const float denom = ((area_p + area_t) - inter) + 1e-6f;
        const float iou   = inter / denom;

        // strict '>' keeps the lowest p within this thread on ties
        if (iou > best) { best = iou; bidx = p; }
    }

    __shared__ float s_iou[256];
    __shared__ int   s_idx[256];
    s_iou[tid] = best;
    s_idx[tid] = bidx;
    __syncthreads();

    // Tree reduction: max iou; on exact tie, lower global index wins
    for (int off = 128; off > 0; off >>= 1) {
        if (tid < off) {
            const float o  = s_iou[tid + off];
            const int   oi = s_idx[tid + off];
            const float m  = s_iou[tid];
            const int   mi = s_idx[tid];
            if (o > m || (o == m && oi < mi)) {
                s_iou[tid] = o;
                s_idx[tid] = oi;
            }
        }
        __syncthreads();
    }

    if (tid == 0) {
        const int bi = s_idx[0];
        const float* mp = pb + bi * 5;
        float sq = 0.0f;
        for (int k = 0; k < 5; ++k) {
            const float d = mp[k] - tb[k];
            sq += d * d;
        }
        const bool valid = (t < lengths[b]);
        ws[bt] = valid ? sq : 0.0f;
    }
}

// Kernel 2: reduce ws[0 .. B*T) -> out[0] = sum / B
__global__ __launch_bounds__(256) void yolo_reduce_kernel(
    const float* __restrict__ ws,
    float* __restrict__ out)
{
    const int tid = threadIdx.x;
    float s = 0.0f;
    for (int i = tid; i < BB * TT; i += 256) s += ws[i];

    __shared__ float sm[256];
    sm[tid] = s;
    __syncthreads();
    for (int off = 128; off > 0; off >>= 1) {
        if (tid < off) sm[tid] += sm[tid + off];
        __syncthreads();
    }
    if (tid == 0) out[0] = sm[0] / (float)BB;
}

extern "C" void kernel_launch(void* const* d_in, const int* in_sizes, int n_in,
                              void* d_out, int out_size, void* d_ws, size_t ws_size,
                              hipStream_t stream) {
    const float* pred    = (const float*)d_in[0]; // [B,P,5] f32
    const float* tgt     = (const float*)d_in[1]; // [B,T,5] f32
    const int*   lengths = (const int*)d_in[2];   // [B] int32
    float* out = (float*)d_out;
    float* ws  = (float*)d_ws;                    // B*T floats = 25.6 KB

    yolo_match_kernel<<<BB * TT, 256, 0, stream>>>(pred, tgt, lengths, ws);
    yolo_reduce_kernel<<<1, 256, 0, stream>>>(ws, out);
}